// Round 1
// baseline (157.105 us; speedup 1.0000x reference)
//
#include <hip/hip_runtime.h>
#include <hip/hip_bf16.h>
#include <stdint.h>

// Problem dims (fixed by reference)
#define N_ROWS 4096
#define D_DIM  512
#define MC     4096
#define KC     2048

typedef unsigned short u16;
typedef __attribute__((ext_vector_type(8))) short bf16x8;
typedef __attribute__((ext_vector_type(4))) float f32x4;

__device__ __forceinline__ u16 f2bf(float f) {
  union { float f; uint32_t u; } v; v.f = f;
  uint32_t u = v.u;
  return (u16)((u + 0x7FFFu + ((u >> 16) & 1u)) >> 16);  // RNE
}

__global__ void zero_f32(float* __restrict__ p, int n) {
  int i = blockIdx.x * blockDim.x + threadIdx.x;
  int stride = gridDim.x * blockDim.x;
  for (; i < n; i += stride) p[i] = 0.f;
}

__global__ void cvt_bf16(const float* __restrict__ in, u16* __restrict__ out, int n) {
  int i = blockIdx.x * blockDim.x + threadIdx.x;
  int stride = gridDim.x * blockDim.x;
  for (; i < n; i += stride) out[i] = f2bf(in[i]);
}

// out[c][r] = bf16(in[r][c]);  in: [R][C] f32, out: [C][R] bf16
__global__ void transpose_cvt(const float* __restrict__ in, u16* __restrict__ out,
                              int R, int C) {
  __shared__ float tile[32][33];
  const int ct = blockIdx.x * 32;
  const int rt = blockIdx.y * 32;
  const int tx = threadIdx.x;   // 0..31
  const int ty = threadIdx.y;   // 0..7
  #pragma unroll
  for (int i = 0; i < 32; i += 8)
    tile[ty + i][tx] = in[(size_t)(rt + ty + i) * C + ct + tx];
  __syncthreads();
  #pragma unroll
  for (int i = 0; i < 32; i += 8)
    out[(size_t)(ct + ty + i) * R + rt + tx] = f2bf(tile[tx][ty + i]);
}

// Generic bf16 GEMM: out[m][n] = sum_k Ag[m][k] * Bg[n][k]   (Bg is B-transposed)
// EPI: 0 = store f32, 1 = atomicAdd f32 (split-K), 2 = distance epilogue
#define BM 128
#define BN 128
#define BK 64
#define LDT (BK + 8)

template <int EPI>
__global__ __launch_bounds__(256)
void gemm_bf16(const u16* __restrict__ Ag, const u16* __restrict__ Bg,
               float* __restrict__ Cf,
               const float* __restrict__ tvec, const float* __restrict__ svec,
               int Mdim, int Ndim, int Kdim) {
  __shared__ __align__(16) u16 As[BM][LDT];
  __shared__ __align__(16) u16 Bs[BN][LDT];

  const int tid = threadIdx.x;
  const int n0 = blockIdx.x * BN;
  const int m0 = blockIdx.y * BM;
  int kBeg = 0, kEnd = Kdim;
  if (gridDim.z > 1) {
    int chunk = Kdim / gridDim.z;
    kBeg = blockIdx.z * chunk;
    kEnd = kBeg + chunk;
  }

  // staging: thread -> (row, 8 contiguous k)
  const int ldr = tid >> 3;          // 0..31
  const int ldk = (tid & 7) << 3;    // 0..56 step 8

  // wave/fragment geometry
  const int lane = tid & 63;
  const int w  = tid >> 6;
  const int wr = (w >> 1) << 6;      // wave row offset (0/64)
  const int wc = (w & 1) << 6;       // wave col offset (0/64)
  const int fr = lane & 15;
  const int fk = (lane >> 4) << 3;

  f32x4 acc[4][4];
  const f32x4 z4 = {0.f, 0.f, 0.f, 0.f};
  #pragma unroll
  for (int i = 0; i < 4; ++i)
    #pragma unroll
    for (int j = 0; j < 4; ++j) acc[i][j] = z4;

  for (int k0 = kBeg; k0 < kEnd; k0 += BK) {
    #pragma unroll
    for (int i = 0; i < 4; ++i) {
      int r = ldr + i * 32;
      uint4 va = *reinterpret_cast<const uint4*>(&Ag[(size_t)(m0 + r) * Kdim + k0 + ldk]);
      *reinterpret_cast<uint4*>(&As[r][ldk]) = va;
      uint4 vb = *reinterpret_cast<const uint4*>(&Bg[(size_t)(n0 + r) * Kdim + k0 + ldk]);
      *reinterpret_cast<uint4*>(&Bs[r][ldk]) = vb;
    }
    __syncthreads();
    #pragma unroll
    for (int kk = 0; kk < BK; kk += 32) {
      bf16x8 a[4], b[4];
      #pragma unroll
      for (int i = 0; i < 4; ++i)
        a[i] = *reinterpret_cast<const bf16x8*>(&As[wr + i * 16 + fr][kk + fk]);
      #pragma unroll
      for (int j = 0; j < 4; ++j)
        b[j] = *reinterpret_cast<const bf16x8*>(&Bs[wc + j * 16 + fr][kk + fk]);
      #pragma unroll
      for (int i = 0; i < 4; ++i)
        #pragma unroll
        for (int j = 0; j < 4; ++j)
          acc[i][j] = __builtin_amdgcn_mfma_f32_16x16x32_bf16(a[i], b[j], acc[i][j], 0, 0, 0);
    }
    __syncthreads();
  }

  // epilogue; C/D: col = lane&15, row = (lane>>4)*4 + reg   [verified mapping]
  #pragma unroll
  for (int i = 0; i < 4; ++i) {
    #pragma unroll
    for (int j = 0; j < 4; ++j) {
      #pragma unroll
      for (int r = 0; r < 4; ++r) {
        int grow = m0 + wr + i * 16 + (lane >> 4) * 4 + r;
        int gcol = n0 + wc + j * 16 + fr;
        size_t idx = (size_t)grow * Ndim + gcol;
        float v = acc[i][j][r];
        if (EPI == 0) {
          Cf[idx] = v;
        } else if (EPI == 1) {
          atomicAdd(&Cf[idx], v);
        } else {
          float sq = tvec[gcol] - 2.f * v + svec[grow];
          Cf[idx] = sqrtf(fmaxf(sq, 0.f));
        }
      }
    }
  }
}

// t[col] = sum_d M[d][col] * A[d][col]   (atomic partial over 32-row chunks)
__global__ void colsum_t(const float* __restrict__ Mm, const float* __restrict__ Af,
                         float* __restrict__ t) {
  int col = blockIdx.x * blockDim.x + threadIdx.x;
  int d0 = blockIdx.y * 32;
  float p = 0.f;
  #pragma unroll 8
  for (int d = d0; d < d0 + 32; ++d)
    p += Mm[(size_t)d * MC + col] * Af[(size_t)d * MC + col];
  atomicAdd(&t[col], p);
}

// s[row] = sum_d C[row][d] * H[row][d]   (one wave per row)
__global__ void rowsum_s(const float* __restrict__ Cc, const float* __restrict__ Hf,
                         float* __restrict__ s) {
  int wave = threadIdx.x >> 6, lane = threadIdx.x & 63;
  int row = blockIdx.x * 4 + wave;
  float p = 0.f;
  #pragma unroll
  for (int d = lane; d < D_DIM; d += 64)
    p += Cc[(size_t)row * D_DIM + d] * Hf[(size_t)row * D_DIM + d];
  #pragma unroll
  for (int off = 32; off > 0; off >>= 1) p += __shfl_down(p, off);
  if (lane == 0) s[row] = p;
}

extern "C" void kernel_launch(void* const* d_in, const int* in_sizes, int n_in,
                              void* d_out, int out_size, void* d_ws, size_t ws_size,
                              hipStream_t stream) {
  const float* X  = (const float*)d_in[0];  // [4096][512]
  const float* Mm = (const float*)d_in[1];  // [512][4096]
  const float* Cc = (const float*)d_in[2];  // [2048][512]
  float* out = (float*)d_out;               // [2048][4096]

  char* ws = (char*)d_ws;
  const size_t MB = 1u << 20;
  u16*   XT_bf = (u16*)(ws);                        // [512][4096] bf16, 4MB
  u16*   C_bf  = (u16*)(ws + 4 * MB);               // [2048][512] bf16, 2MB
  float* G_f   = (float*)(ws + 6 * MB);             // [512][512] f32, 1MB
  u16*   G_bf  = (u16*)(ws + 7 * MB);               // 0.5MB
  u16*   M_bfT = (u16*)(ws + 7 * MB + 512 * 1024);  // [4096][512] bf16, 4MB
  float* A_f   = (float*)(ws + 11 * MB + 512 * 1024); // [512][4096] f32, 8MB
  u16*   A_bfT = (u16*)(ws + 19 * MB + 512 * 1024); // [4096][512] bf16, 4MB
  float* H_f   = (float*)(ws + 23 * MB + 512 * 1024); // [2048][512] f32, 4MB
  float* tvec  = (float*)(ws + 27 * MB + 512 * 1024); // [4096] f32
  float* svec  = (float*)(ws + 27 * MB + 512 * 1024 + 16 * 1024); // [2048] f32

  dim3 tb(32, 8);

  // ws is poisoned 0xAA every call: zero the atomic-accumulated buffers.
  zero_f32<<<256, 256, 0, stream>>>(G_f, 512 * 512);
  zero_f32<<<16, 256, 0, stream>>>(tvec, 4096);

  // XT_bf[d][n] = bf16(X[n][d])
  transpose_cvt<<<dim3(512 / 32, 4096 / 32), tb, 0, stream>>>(X, XT_bf, 4096, 512);
  // C_bf = bf16(C)
  cvt_bf16<<<2048, 256, 0, stream>>>(Cc, C_bf, 2048 * 512);

  // G = X^T X : A-op = XT_bf [512][4096], BT-op = XT_bf, split-K=8, atomic f32
  gemm_bf16<1><<<dim3(512 / BN, 512 / BM, 8), 256, 0, stream>>>(
      XT_bf, XT_bf, G_f, nullptr, nullptr, 512, 512, 4096);
  cvt_bf16<<<1024, 256, 0, stream>>>(G_f, G_bf, 512 * 512);

  // M_bfT[m][d] = bf16(M[d][m])
  transpose_cvt<<<dim3(4096 / 32, 512 / 32), tb, 0, stream>>>(Mm, M_bfT, 512, 4096);

  // A = G @ M : [512][4096] f32
  gemm_bf16<0><<<dim3(4096 / BN, 512 / BM, 1), 256, 0, stream>>>(
      G_bf, M_bfT, A_f, nullptr, nullptr, 512, 4096, 512);
  // A_bfT[m][d] = bf16(A[d][m])
  transpose_cvt<<<dim3(4096 / 32, 512 / 32), tb, 0, stream>>>(A_f, A_bfT, 512, 4096);
  // t[m] = sum_d M[d][m] * A[d][m]
  colsum_t<<<dim3(4096 / 256, 512 / 32), 256, 0, stream>>>(Mm, A_f, tvec);

  // H = C @ G : [2048][512] f32   (G symmetric -> BT-op = G_bf)
  gemm_bf16<0><<<dim3(512 / BN, 2048 / BM, 1), 256, 0, stream>>>(
      C_bf, G_bf, H_f, nullptr, nullptr, 2048, 512, 512);
  // s[k] = sum_d C[k][d] * H[k][d]
  rowsum_s<<<2048 / 4, 256, 0, stream>>>(Cc, H_f, svec);

  // out[k][m] = sqrt(max(t[m] - 2*(C@A)[k][m] + s[k], 0))
  gemm_bf16<2><<<dim3(4096 / BN, 2048 / BM, 1), 256, 0, stream>>>(
      C_bf, A_bfT, out, tvec, svec, 2048, 4096, 512);
}

// Round 2
// 152.484 us; speedup vs baseline: 1.0303x; 1.0303x over previous
//
#include <hip/hip_runtime.h>
#include <stdint.h>

// Problem dims (fixed by reference)
#define NR    4096   // sampled activations
#define D_DIM 512
#define MC    4096   // M columns
#define KC    2048   // centroids

typedef unsigned short u16;
typedef __attribute__((ext_vector_type(8))) short bf16x8;
typedef __attribute__((ext_vector_type(4))) float f32x4;

__device__ __forceinline__ u16 f2bf(float f) {
  union { float f; uint32_t u; } v; v.f = f;
  return (u16)((v.u + 0x7FFFu + ((v.u >> 16) & 1u)) >> 16);  // RNE
}
__device__ __forceinline__ float bf2f(u16 h) {
  union { uint32_t u; float f; } v; v.u = (uint32_t)h << 16; return v.f;
}

// async global->LDS, 16B per lane. LDS dest must be wave-uniform base (+lane*16 by HW).
__device__ __forceinline__ void gload16(const void* g, void* lds) {
  __builtin_amdgcn_global_load_lds((const __attribute__((address_space(1))) void*)g,
                                   (__attribute__((address_space(3))) void*)lds,
                                   16, 0, 0);
}

__global__ void zero_f32(float* __restrict__ p, int n) {
  int i = blockIdx.x * blockDim.x + threadIdx.x;
  int stride = gridDim.x * blockDim.x;
  for (; i < n; i += stride) p[i] = 0.f;
}

__global__ void cvt_bf16(const float* __restrict__ in, u16* __restrict__ out, int n) {
  int i = blockIdx.x * blockDim.x + threadIdx.x;
  int stride = gridDim.x * blockDim.x;
  for (; i < n; i += stride) out[i] = f2bf(in[i]);
}

// G_bf[i] = bf16( sum_z part[z][i] ), n = 512*512, z = 8
__global__ void reduce_cvt_g(const float* __restrict__ part, u16* __restrict__ gbf, int n) {
  int i = blockIdx.x * blockDim.x + threadIdx.x;
  if (i < n) {
    float s = 0.f;
    #pragma unroll
    for (int z = 0; z < 8; ++z) s += part[(size_t)z * n + i];
    gbf[i] = f2bf(s);
  }
}

// out[c][r] = bf16(in[r][c]);  in: [R][C] f32, out: [C][R] bf16
__global__ void transpose_cvt(const float* __restrict__ in, u16* __restrict__ out,
                              int R, int C) {
  __shared__ float tile[32][33];
  const int ct = blockIdx.x * 32;
  const int rt = blockIdx.y * 32;
  const int tx = threadIdx.x;   // 0..31
  const int ty = threadIdx.y;   // 0..7
  #pragma unroll
  for (int i = 0; i < 32; i += 8)
    tile[ty + i][tx] = in[(size_t)(rt + ty + i) * C + ct + tx];
  __syncthreads();
  #pragma unroll
  for (int i = 0; i < 32; i += 8)
    out[(size_t)(ct + ty + i) * R + rt + tx] = f2bf(tile[tx][ty + i]);
}

// m97-structure bf16 GEMM: out[m][n] = sum_k Ag[m][k]*Bg[n][k]  (both row-major [rows][K])
// 128x128 tile, BK=64, 4 waves, linear LDS, global_load_lds width=16.
// EPI 0: store f32 partials at Cf + blockIdx.z*M*N   (split-K)
// EPI 2: distance epilogue: Cf = sqrt(max(tv[col] - 2v + sv[row], 0))
// EPI 3: store bf16 to Cbf; atomicAdd vatom[row] += sum_col v * bf16(DotH[row][col])
// EPI 4: no store; atomicAdd vatom[row] += sum_col v * DotF[row][col]   (split-K ok)
#define BM 128
#define BN 128
#define BK 64

template <int EPI>
__global__ __launch_bounds__(256)
void gemm97(const u16* __restrict__ Ag, const u16* __restrict__ Bg,
            float* __restrict__ Cf, u16* __restrict__ Cbf,
            const u16* __restrict__ DotH, const float* __restrict__ DotF,
            float* __restrict__ vatom,
            const float* __restrict__ tv, const float* __restrict__ sv,
            int Mdim, int Ndim, int Kdim) {
  __shared__ __align__(16) u16 As[BM][BK];   // 16KB, linear (layout fixed by gload16)
  __shared__ __align__(16) u16 Bs[BN][BK];   // 16KB

  const int tid = threadIdx.x;
  const int n0 = blockIdx.x * BN;
  const int m0 = blockIdx.y * BM;
  int kBeg = 0, kEnd = Kdim;
  if (gridDim.z > 1) { int ch = Kdim / gridDim.z; kBeg = blockIdx.z * ch; kEnd = kBeg + ch; }

  // staging geometry: call c stages rows [c*32, c*32+32), thread -> (row, 8 k-elems)
  const int rowt = tid >> 3;           // 0..31
  const int colt = (tid & 7) << 3;     // 0..56 step 8
  const int wave = tid >> 6;
  const int lane = tid & 63;
  const int wr = (wave >> 1) << 6;
  const int wc = (wave & 1) << 6;
  const int fr = lane & 15;
  const int fk = (lane >> 4) << 3;
  char* AsB = (char*)&As[0][0];
  char* BsB = (char*)&Bs[0][0];
  const int wb = wave << 10;           // wave-uniform LDS byte base

  f32x4 acc[4][4] = {};

  for (int k0 = kBeg; k0 < kEnd; k0 += BK) {
    const u16* ag = Ag + (size_t)(m0 + rowt) * Kdim + k0 + colt;
    const u16* bg = Bg + (size_t)(n0 + rowt) * Kdim + k0 + colt;
    #pragma unroll
    for (int c = 0; c < 4; ++c) {
      gload16(ag + (size_t)(c * 32) * Kdim, AsB + c * 4096 + wb);
      gload16(bg + (size_t)(c * 32) * Kdim, BsB + c * 4096 + wb);
    }
    __syncthreads();   // compiler emits vmcnt(0) drain before barrier
    #pragma unroll
    for (int kk = 0; kk < BK; kk += 32) {
      bf16x8 a[4], b[4];
      #pragma unroll
      for (int i = 0; i < 4; ++i) a[i] = *(const bf16x8*)&As[wr + i * 16 + fr][kk + fk];
      #pragma unroll
      for (int j = 0; j < 4; ++j) b[j] = *(const bf16x8*)&Bs[wc + j * 16 + fr][kk + fk];
      #pragma unroll
      for (int i = 0; i < 4; ++i)
        #pragma unroll
        for (int j = 0; j < 4; ++j)
          acc[i][j] = __builtin_amdgcn_mfma_f32_16x16x32_bf16(a[i], b[j], acc[i][j], 0, 0, 0);
    }
    __syncthreads();
  }

  // C/D mapping (verified): col = lane&15, row = (lane>>4)*4 + reg
  const int q = lane >> 4;
  #pragma unroll
  for (int i = 0; i < 4; ++i) {
    #pragma unroll
    for (int r = 0; r < 4; ++r) {
      const int grow = m0 + wr + i * 16 + q * 4 + r;
      float p = 0.f;
      #pragma unroll
      for (int j = 0; j < 4; ++j) {
        const int gcol = n0 + wc + j * 16 + fr;
        const float v = acc[i][j][r];
        const size_t idx = (size_t)grow * Ndim + gcol;
        if (EPI == 0) Cf[(size_t)blockIdx.z * Mdim * Ndim + idx] = v;
        if (EPI == 2) { float sq = tv[gcol] - 2.f * v + sv[grow]; Cf[idx] = sqrtf(fmaxf(sq, 0.f)); }
        if (EPI == 3) { Cbf[idx] = f2bf(v); p += v * bf2f(DotH[idx]); }
        if (EPI == 4) { p += v * DotF[idx]; }
      }
      if (EPI == 3 || EPI == 4) {
        #pragma unroll
        for (int off = 1; off < 16; off <<= 1) p += __shfl_xor(p, off);
        if (fr == 0) atomicAdd(&vatom[grow], p);
      }
    }
  }
}

extern "C" void kernel_launch(void* const* d_in, const int* in_sizes, int n_in,
                              void* d_out, int out_size, void* d_ws, size_t ws_size,
                              hipStream_t stream) {
  const float* X  = (const float*)d_in[0];  // [4096][512]
  const float* Mm = (const float*)d_in[1];  // [512][4096]
  const float* Cc = (const float*)d_in[2];  // [2048][512]
  float* out = (float*)d_out;               // [2048][4096]

  char* ws = (char*)d_ws;
  const size_t MB = 1u << 20;
  u16*   XT_bf = (u16*)(ws);                 // [512][4096] bf16, 4MB
  u16*   C_bf  = (u16*)(ws + 4 * MB);        // [2048][512] bf16, 2MB
  u16*   M_bfT = (u16*)(ws + 6 * MB);        // [4096][512] bf16, 4MB  (M^T)
  u16*   A_bfT = (u16*)(ws + 10 * MB);       // [4096][512] bf16, 4MB  (A^T = (G M)^T)
  u16*   G_bf  = (u16*)(ws + 14 * MB);       // [512][512] bf16, 0.5MB
  float* Gpart = (float*)(ws + 14 * MB + 512 * 1024);  // 8 x [512][512] f32, 8MB
  float* tvec  = (float*)(ws + 22 * MB + 512 * 1024);  // [4096] f32
  float* svec  = (float*)(ws + 22 * MB + 512 * 1024 + 16 * 1024);  // [2048] f32

  // tvec+svec are atomic-accumulated; ws is re-poisoned 0xAA each call -> zero them.
  zero_f32<<<24, 256, 0, stream>>>(tvec, 4096 + 2048);

  // XT_bf[d][n] = bf16(X[n][d]);  C_bf = bf16(C);  M_bfT[m][d] = bf16(M[d][m])
  transpose_cvt<<<dim3(16, 128), dim3(32, 8), 0, stream>>>(X, XT_bf, 4096, 512);
  cvt_bf16<<<1024, 256, 0, stream>>>(Cc, C_bf, 2048 * 512);
  transpose_cvt<<<dim3(128, 16), dim3(32, 8), 0, stream>>>(Mm, M_bfT, 512, 4096);

  // G = X^T X, split-K z=8 into f32 partials, then reduce + cvt to bf16
  gemm97<0><<<dim3(4, 4, 8), 256, 0, stream>>>(
      XT_bf, XT_bf, Gpart, nullptr, nullptr, nullptr, nullptr, nullptr, nullptr,
      512, 512, 4096);
  reduce_cvt_g<<<1024, 256, 0, stream>>>(Gpart, G_bf, 512 * 512);

  // A^T = M^T G (G symmetric): out[m][d], stored bf16 directly; fused t[m] += sum_d v*M^T[m][d]
  gemm97<3><<<dim3(4, 32), 256, 0, stream>>>(
      M_bfT, G_bf, nullptr, A_bfT, M_bfT, nullptr, tvec, nullptr, nullptr,
      4096, 512, 512);

  // s[k] = c_k^T G c_k fused: H=C*G never stored; split-K z=4 (s is linear in H)
  gemm97<4><<<dim3(4, 16, 4), 256, 0, stream>>>(
      C_bf, G_bf, nullptr, nullptr, nullptr, Cc, svec, nullptr, nullptr,
      2048, 512, 512);

  // out[k][m] = sqrt(max(t[m] - 2*(C A^T)[k][m] + s[k], 0))
  gemm97<2><<<dim3(32, 16), 256, 0, stream>>>(
      C_bf, A_bfT, out, nullptr, nullptr, nullptr, nullptr, tvec, svec,
      2048, 4096, 512);
}